// Round 4
// baseline (1015.200 us; speedup 1.0000x reference)
//
#include <hip/hip_runtime.h>

#define N 2048
#define NG 8
#define NBLK 512

__device__ __forceinline__ float lrelu(float x) { return x > 0.f ? x : 0.2f * x; }

// Monotonic grid-barrier counter. Lives in module .data (NOT the poisoned
// workspace) and survives hipGraph replays: each barrier passage waits for the
// counter to reach the next multiple of NBLK, so it never needs resetting.
__device__ int g_barCnt = 0;

// All-block barrier. Safe because grid (512 blocks, 256 thr, 24.96 KB LDS,
// VGPR<=256 via __launch_bounds__(256,2)) co-resides at 2 blocks/CU on 256 CUs.
// Spin polls are atomic RMWs (device scope, coherent point) — plain loads could
// spin forever on a stale per-XCD L2 line. s_sleep backoff keeps contention low.
__device__ __forceinline__ void gridBarrier() {
  __threadfence();                       // release this block's writes
  __syncthreads();
  if (threadIdx.x == 0) {
    int t = atomicAdd(&g_barCnt, 1) + 1;
    int target = ((t - 1) / NBLK + 1) * NBLK;
    if (t != target) {
      while (atomicAdd(&g_barCnt, 0) < target) __builtin_amdgcn_s_sleep(16);
    }
  }
  __syncthreads();
  __threadfence();                       // acquire remote writes
}

struct KP {
  const float* attn; const float* w_agg; const float* b_agg; const float* x;
  const float* W1; const float* att_src1; const float* att_dst1;
  const float* We1; const float* att_e1; const float* bias1;
  const float* W2; const float* att_src2; const float* att_dst2;
  const float* We2; const float* att_e2; const float* bias2;
  const float* W_lin; const float* b_lin; const int* bidx;
  float* edge_out; float* colSum; float* colCnt; float* z1; float* z2;
  float* gsum; float* gcnt; float* wev;
  float* h1; float* a_s1; float* a_d1; float* hh2; float* a_s2; float* a_d2;
  float* partials; float* out;
};

__global__ __launch_bounds__(256, 2) void megaK(KP p) {
  __shared__ float smem[6240];   // max user: phase B  pL[16][260] + hT[8][260]
  const int tid = threadIdx.x;
  const int b = blockIdx.x;

  // ---------- phase Z: zero reduction buffers (colSum|colCnt|z1|z2|gsum|gcnt) ----------
  {
    const int total = 7 * N + 520;
    int i = b * 256 + tid;
    if (i < total) p.colSum[i] = 0.f;
  }
  gridBarrier();

  // ---------- phase A: agg stripe (32 rows x 256 cols) + h1 chunk (4 nodes) ----------
  {
    float wreg[12];
#pragma unroll
    for (int k = 0; k < 12; ++k) wreg[k] = p.w_agg[k];
    const float bb = p.b_agg[0];
    const int i0 = (b >> 3) * 32, j0 = (b & 7) * 256;
    const int j = j0 + tid;
    float csA = 0.f, ccA = 0.f;
#pragma unroll 2
    for (int r = 0; r < 32; ++r) {
      int i = i0 + r;
      const float* pp = p.attn + (size_t)i * N + j;
      float v = bb;
#pragma unroll
      for (int k = 0; k < 12; ++k) v += wreg[k] * pp[(size_t)k * N * N];
      float e = v > 0.f ? v : 0.f;
      p.edge_out[(size_t)i * N + j] = e;
      if (e > 0.f && i != j) { csA += e; ccA += 1.f; }
    }
    atomicAdd(&p.colSum[j], csA);
    atomicAdd(&p.colCnt[j], ccA);

    // h1 = x @ W1, a_s1, a_d1; block 0 also computes we[]
    float* xr = smem;
    const int n0 = b * 4;
    if (b == 0) {
      float v1 = p.We1[tid] * p.att_e1[tid];
#pragma unroll
      for (int off = 32; off > 0; off >>= 1) v1 += __shfl_down(v1, off);
      int lane = tid & 63, wid = tid >> 6;
      if (lane == 0) p.wev[wid] = v1;
      float v2 = (tid < 64) ? p.We2[tid] * p.att_e2[tid] : 0.f;
#pragma unroll
      for (int off = 32; off > 0; off >>= 1) v2 += __shfl_down(v2, off);
      if (tid == 0) p.wev[4] = v2;
    }
    for (int t = tid; t < 512; t += 256) xr[t] = p.x[n0 * 128 + t];
    __syncthreads();
    float acc[4] = {0.f, 0.f, 0.f, 0.f};
    for (int k = 0; k < 128; ++k) {
      float wv = p.W1[k * 256 + tid];
#pragma unroll
      for (int r = 0; r < 4; ++r) acc[r] += xr[r * 128 + k] * wv;
    }
    float asw = p.att_src1[tid], adw = p.att_dst1[tid];
    int lane = tid & 63, head = tid >> 6;
#pragma unroll
    for (int r = 0; r < 4; ++r) {
      p.h1[(size_t)(n0 + r) * 256 + tid] = acc[r];
      float ps = acc[r] * asw, pd = acc[r] * adw;
#pragma unroll
      for (int off = 32; off > 0; off >>= 1) { ps += __shfl_down(ps, off); pd += __shfl_down(pd, off); }
      if (lane == 0) { p.a_s1[(n0 + r) * 4 + head] = ps; p.a_d1[(n0 + r) * 4 + head] = pd; }
    }
  }
  gridBarrier();

  // ---------- phase B: layer1 PV (unnormalized softmax, z1 via atomics) ----------
  {
    const int bx = b & 31, by = b >> 5;
    const int d0 = bx * 64;
    const int sBeg = by * 128;
    float (*hT)[260] = (float (*)[260])smem;            // [8][260]  (two halves)
    float (*pL)[260] = (float (*)[260])(smem + 2080);   // [16][260]
    float w0 = p.wev[0], w1 = p.wev[1], w2 = p.wev[2], w3 = p.wev[3];
    int ssp = tid & 15, dq = tid >> 4;
    float4 ad4[4];
    float me_[4];
#pragma unroll
    for (int q = 0; q < 4; ++q) {
      int d = d0 + dq * 4 + q;
      ad4[q] = *(const float4*)(p.a_d1 + d * 4);
      float c = p.colCnt[d];
      me_[q] = c > 0.f ? p.colSum[d] / c : 0.f;
    }
    float zac[4][4];
#pragma unroll
    for (int q = 0; q < 4; ++q)
#pragma unroll
      for (int h = 0; h < 4; ++h) zac[q][h] = 0.f;
    int dg = tid & 7;
    int cb = (tid >> 3) * 8;
    int hh = tid >> 6;
    float acc[8][8];
#pragma unroll
    for (int i = 0; i < 8; ++i)
#pragma unroll
      for (int jj = 0; jj < 8; ++jj) acc[i][jj] = 0.f;

    int c4 = (tid & 63) * 4;
    int rb2 = (tid >> 6) * 2;

#pragma unroll 1
    for (int s0 = sBeg; s0 < sBeg + 128; s0 += 16) {
      // p-compute: pL[ssp][h*64+dd] for all 16 ssp rows
      {
        int s = s0 + ssp;
        float4 as4 = *(const float4*)(p.a_s1 + s * 4);
        float4 av4 = *(const float4*)(p.edge_out + (size_t)s * N + d0 + dq * 4);
        float ev_[4] = {av4.x, av4.y, av4.z, av4.w};
        float pq[4][4];
#pragma unroll
        for (int q = 0; q < 4; ++q) {
          int d = d0 + dq * 4 + q;
          float av = ev_[q];
          float ev; bool inc;
          if (s == d) { ev = me_[q]; inc = true; } else { ev = av; inc = av > 0.f; }
          float p0 = inc ? __expf(lrelu(as4.x + ad4[q].x + ev * w0)) : 0.f;
          float p1 = inc ? __expf(lrelu(as4.y + ad4[q].y + ev * w1)) : 0.f;
          float p2 = inc ? __expf(lrelu(as4.z + ad4[q].z + ev * w2)) : 0.f;
          float p3 = inc ? __expf(lrelu(as4.w + ad4[q].w + ev * w3)) : 0.f;
          pq[0][q] = p0; pq[1][q] = p1; pq[2][q] = p2; pq[3][q] = p3;
          zac[q][0] += p0; zac[q][1] += p1; zac[q][2] += p2; zac[q][3] += p3;
        }
#pragma unroll
        for (int h = 0; h < 4; ++h)
          *(float4*)(&pL[ssp][h * 64 + dq * 4]) = make_float4(pq[h][0], pq[h][1], pq[h][2], pq[h][3]);
      }
      // half 0: stage hT rows 0..7 (= s0..s0+7)
#pragma unroll
      for (int p4 = 0; p4 < 2; ++p4) {
        int r = rb2 + p4;
        *(float4*)(&hT[r][c4]) = *(const float4*)(p.h1 + (size_t)(s0 + r) * 256 + c4);
      }
      __syncthreads();
#pragma unroll
      for (int ss = 0; ss < 8; ++ss) {
        float4 pA = *(const float4*)(&pL[ss][hh * 64 + dg * 8]);
        float4 pB = *(const float4*)(&pL[ss][hh * 64 + dg * 8 + 4]);
        float4 hA = *(const float4*)(&hT[ss][cb]);
        float4 hB = *(const float4*)(&hT[ss][cb + 4]);
        float pv[8] = {pA.x, pA.y, pA.z, pA.w, pB.x, pB.y, pB.z, pB.w};
        float hv[8] = {hA.x, hA.y, hA.z, hA.w, hB.x, hB.y, hB.z, hB.w};
#pragma unroll
        for (int di = 0; di < 8; ++di)
#pragma unroll
          for (int ci = 0; ci < 8; ++ci) acc[di][ci] += pv[di] * hv[ci];
      }
      __syncthreads();
      // half 1: stage hT rows 0..7 (= s0+8..s0+15)
#pragma unroll
      for (int p4 = 0; p4 < 2; ++p4) {
        int r = rb2 + p4;
        *(float4*)(&hT[r][c4]) = *(const float4*)(p.h1 + (size_t)(s0 + 8 + r) * 256 + c4);
      }
      __syncthreads();
#pragma unroll
      for (int ss = 8; ss < 16; ++ss) {
        float4 pA = *(const float4*)(&pL[ss][hh * 64 + dg * 8]);
        float4 pB = *(const float4*)(&pL[ss][hh * 64 + dg * 8 + 4]);
        float4 hA = *(const float4*)(&hT[ss - 8][cb]);
        float4 hB = *(const float4*)(&hT[ss - 8][cb + 4]);
        float pv[8] = {pA.x, pA.y, pA.z, pA.w, pB.x, pB.y, pB.z, pB.w};
        float hv[8] = {hA.x, hA.y, hA.z, hA.w, hB.x, hB.y, hB.z, hB.w};
#pragma unroll
        for (int di = 0; di < 8; ++di)
#pragma unroll
          for (int ci = 0; ci < 8; ++ci) acc[di][ci] += pv[di] * hv[ci];
      }
      __syncthreads();
    }
    float* outp = p.partials + (size_t)by * ((size_t)N * 256);
#pragma unroll
    for (int di = 0; di < 8; ++di) {
      size_t rowo = (size_t)(d0 + dg * 8 + di) * 256 + cb;
      *(float4*)(outp + rowo) = make_float4(acc[di][0], acc[di][1], acc[di][2], acc[di][3]);
      *(float4*)(outp + rowo + 4) = make_float4(acc[di][4], acc[di][5], acc[di][6], acc[di][7]);
    }
#pragma unroll
    for (int q = 0; q < 4; ++q)
#pragma unroll
      for (int h = 0; h < 4; ++h) {
        float v = zac[q][h];
        v += __shfl_down(v, 8); v += __shfl_down(v, 4);
        v += __shfl_down(v, 2); v += __shfl_down(v, 1);
        if (ssp == 0) atomicAdd(&p.z1[(d0 + dq * 4 + q) * 4 + h], v);
      }
  }
  gridBarrier();

  // ---------- phase C: layer1 finalize + h2 features ----------
  {
    float (*hr)[256] = (float (*)[256])smem;
    const int n0 = b * 4;
    for (int e = tid; e < 1024; e += 256) {
      int node = e >> 8, c = e & 255;
      size_t base = (size_t)(n0 + node) * 256 + c;
      float sAcc = 0.f;
#pragma unroll
      for (int q = 0; q < 16; ++q) sAcc += p.partials[(size_t)q * N * 256 + base];
      float a = sAcc / p.z1[(n0 + node) * 4 + (c >> 6)] + p.bias1[c];
      hr[node][c] = a > 0.f ? a : __expf(a) - 1.f;
    }
    __syncthreads();
    int c = tid & 63, nl = tid >> 6;
    float acc = 0.f;
    for (int k = 0; k < 256; ++k) acc += hr[nl][k] * p.W2[k * 64 + c];
    p.hh2[(size_t)(n0 + nl) * 64 + c] = acc;
    float ps = acc * p.att_src2[c], pd = acc * p.att_dst2[c];
#pragma unroll
    for (int off = 32; off > 0; off >>= 1) { ps += __shfl_down(ps, off); pd += __shfl_down(pd, off); }
    if (c == 0) { p.a_s2[n0 + nl] = ps; p.a_d2[n0 + nl] = pd; }
  }
  gridBarrier();

  // ---------- phase D: layer2 PV (unnormalized, z2 via atomics) ----------
  {
    const int bx = b & 15, by = b >> 4;
    const int d0 = bx * 128;
    const int sBeg = by * 64;
    float (*hT)[68]  = (float (*)[68])smem;             // [16][68]
    float (*pL)[132] = (float (*)[132])(smem + 1088);   // [16][132]
    float wE = p.wev[4];
    int ssp = tid & 15, dq = tid >> 4;
    float adv[8], me_[8];
#pragma unroll
    for (int q = 0; q < 8; ++q) {
      int d = d0 + dq * 8 + q;
      adv[q] = p.a_d2[d];
      float c = p.colCnt[d];
      me_[q] = c > 0.f ? p.colSum[d] / c : 0.f;
    }
    float zac[8];
#pragma unroll
    for (int q = 0; q < 8; ++q) zac[q] = 0.f;
    int dg = tid & 15;
    int cg2 = tid >> 4;
    float acc[8][4];
#pragma unroll
    for (int i = 0; i < 8; ++i)
#pragma unroll
      for (int jj = 0; jj < 4; ++jj) acc[i][jj] = 0.f;

    int stR = tid >> 4, stC = (tid & 15) * 4;

#pragma unroll 1
    for (int s0 = sBeg; s0 < sBeg + 64; s0 += 16) {
      *(float4*)(&hT[stR][stC]) = *(const float4*)(p.hh2 + (size_t)(s0 + stR) * 64 + stC);
      {
        int s = s0 + ssp;
        float asv = p.a_s2[s];
        float4 eA = *(const float4*)(p.edge_out + (size_t)s * N + d0 + dq * 8);
        float4 eB = *(const float4*)(p.edge_out + (size_t)s * N + d0 + dq * 8 + 4);
        float ev_[8] = {eA.x, eA.y, eA.z, eA.w, eB.x, eB.y, eB.z, eB.w};
        float pq[8];
#pragma unroll
        for (int q = 0; q < 8; ++q) {
          int d = d0 + dq * 8 + q;
          float av = ev_[q];
          float ev; bool inc;
          if (s == d) { ev = me_[q]; inc = true; } else { ev = av; inc = av > 0.f; }
          float pz = inc ? __expf(lrelu(asv + adv[q] + ev * wE)) : 0.f;
          pq[q] = pz;
          zac[q] += pz;
        }
        *(float4*)(&pL[ssp][dq * 8])     = make_float4(pq[0], pq[1], pq[2], pq[3]);
        *(float4*)(&pL[ssp][dq * 8 + 4]) = make_float4(pq[4], pq[5], pq[6], pq[7]);
      }
      __syncthreads();
#pragma unroll
      for (int ss = 0; ss < 16; ++ss) {
        float4 pA = *(const float4*)(&pL[ss][dg * 8]);
        float4 pB = *(const float4*)(&pL[ss][dg * 8 + 4]);
        float4 hA = *(const float4*)(&hT[ss][cg2 * 4]);
        float pv[8] = {pA.x, pA.y, pA.z, pA.w, pB.x, pB.y, pB.z, pB.w};
        float hv[4] = {hA.x, hA.y, hA.z, hA.w};
#pragma unroll
        for (int di = 0; di < 8; ++di)
#pragma unroll
          for (int ci = 0; ci < 4; ++ci) acc[di][ci] += pv[di] * hv[ci];
      }
      __syncthreads();
    }
    float* outp = p.partials + (size_t)by * ((size_t)N * 64);
#pragma unroll
    for (int di = 0; di < 8; ++di) {
      size_t rowo = (size_t)(d0 + dg * 8 + di) * 64 + cg2 * 4;
      *(float4*)(outp + rowo) = make_float4(acc[di][0], acc[di][1], acc[di][2], acc[di][3]);
    }
#pragma unroll
    for (int q = 0; q < 8; ++q) {
      float v = zac[q];
      v += __shfl_down(v, 8); v += __shfl_down(v, 4);
      v += __shfl_down(v, 2); v += __shfl_down(v, 1);
      if (ssp == 0) atomicAdd(&p.z2[d0 + dq * 8 + q], v);
    }
  }
  gridBarrier();

  // ---------- phase E: layer2 finalize + pooled sums ----------
  {
    int i = b * 256 + tid;
    int d = i >> 6, c = i & 63;
    float s = 0.f;
#pragma unroll
    for (int q = 0; q < 32; ++q) s += p.partials[(size_t)q * N * 64 + i];
    float a = s / p.z2[d] + p.bias2[c];
    float v = a > 0.f ? a : __expf(a) - 1.f;
    int g = p.bidx[d];
    atomicAdd(&p.gsum[g * 64 + c], v);
    if (c == 0) atomicAdd(&p.gcnt[g], 1.f);
  }
  gridBarrier();

  // ---------- final: global mean pool + linear (block 0 only) ----------
  if (b == 0) {
    float* gm   = smem;        // 512
    float* cnt_ = smem + 512;  // 8
    if (tid < NG) cnt_[tid] = p.gcnt[tid];
    __syncthreads();
    for (int e = tid; e < NG * 64; e += 256) {
      gm[e] = p.gsum[e] / fmaxf(cnt_[e >> 6], 1.f);
    }
    __syncthreads();
    if (tid < NG * 10) {
      int bb2 = tid / 10, oo = tid % 10;
      float accv = p.b_lin[oo];
      for (int k = 0; k < 64; ++k) accv += gm[bb2 * 64 + k] * p.W_lin[k * 10 + oo];
      p.out[bb2 * 10 + oo] = accv;
    }
  }
}

extern "C" void kernel_launch(void* const* d_in, const int* in_sizes, int n_in,
                              void* d_out, int out_size, void* d_ws, size_t ws_size,
                              hipStream_t stream) {
  KP hp;
  hp.x        = (const float*)d_in[0];
  hp.attn     = (const float*)d_in[1];
  hp.bidx     = (const int*)d_in[2];
  hp.w_agg    = (const float*)d_in[3];
  hp.b_agg    = (const float*)d_in[4];
  hp.W1       = (const float*)d_in[5];
  hp.att_src1 = (const float*)d_in[6];
  hp.att_dst1 = (const float*)d_in[7];
  hp.We1      = (const float*)d_in[8];
  hp.att_e1   = (const float*)d_in[9];
  hp.bias1    = (const float*)d_in[10];
  hp.W2       = (const float*)d_in[11];
  hp.att_src2 = (const float*)d_in[12];
  hp.att_dst2 = (const float*)d_in[13];
  hp.We2      = (const float*)d_in[14];
  hp.att_e2   = (const float*)d_in[15];
  hp.bias2    = (const float*)d_in[16];
  hp.W_lin    = (const float*)d_in[17];
  hp.b_lin    = (const float*)d_in[18];

  float* out = (float*)d_out;
  hp.out = out;
  hp.edge_out = out + 80;

  float* w = (float*)d_ws;
  size_t o = 0;
  float* zb = w + o; o += 7 * N + 1024;   // colSum|colCnt|z1(4N)|z2(N)|gsum(512)|gcnt(8)
  hp.wev  = w + o; o += 8;
  hp.h1   = w + o; o += (size_t)N * 256;
  hp.a_s1 = w + o; o += (size_t)N * 4;
  hp.a_d1 = w + o; o += (size_t)N * 4;
  hp.hh2  = w + o; o += (size_t)N * 64;
  hp.a_s2 = w + o; o += N;
  hp.a_d2 = w + o; o += N;
  hp.partials = w + o; o += (size_t)16 * N * 256;  // phase D reuses (needs 32*N*64 = half)

  hp.colSum = zb;
  hp.colCnt = zb + N;
  hp.z1     = zb + 2 * N;
  hp.z2     = zb + 6 * N;
  hp.gsum   = zb + 7 * N;
  hp.gcnt   = zb + 7 * N + 512;

  megaK<<<dim3(NBLK), dim3(256), 0, stream>>>(hp);
}

// Round 5
// 674.541 us; speedup vs baseline: 1.5050x; 1.5050x over previous
//
#include <hip/hip_runtime.h>

#define N 2048
#define NG 8
#define NBLK 512

__device__ __forceinline__ float lrelu(float x) { return x > 0.f ? x : 0.2f * x; }

// Monotonic grid-barrier counter. Lives in module .data (NOT the poisoned
// workspace) and survives hipGraph replays: each barrier passage waits for the
// counter to reach the next multiple of NBLK, so it never needs resetting.
__device__ int g_barCnt = 0;

// All-block barrier. Safe because grid (512 blocks, 256 thr, 24.96 KB LDS,
// VGPR<=256 via __launch_bounds__(256,2)) co-resides at 2 blocks/CU on 256 CUs.
//
// v2 (round-4 post-mortem): the v1 barrier polled with atomicAdd(&cnt,0) — an
// RMW. 512 pollers bouncing one line in exclusive state serialized the
// coherent point and queued the arrival increments behind the polls; plus all
// 256 threads executed __threadfence() (cache-wide wbL2/inv) per barrier.
// v2: one ACQ_REL fetch_add per block (release = one L2 writeback; the
// preceding __syncthreads already implies vmcnt(0) so the whole block's stores
// are in L2); poll with RELAXED agent-scope atomic LOADs (read the coherent
// point, no ownership, no per-poll invalidate); ONE acquire load on exit.
__device__ __forceinline__ void gridBarrier() {
  __syncthreads();   // compiler emits s_waitcnt vmcnt(0) before s_barrier: block's stores are in L2
  if (threadIdx.x == 0) {
    int t = __hip_atomic_fetch_add(&g_barCnt, 1, __ATOMIC_ACQ_REL, __HIP_MEMORY_SCOPE_AGENT) + 1;
    int target = ((t - 1) / NBLK + 1) * NBLK;
    if (t != target) {
      while (__hip_atomic_load(&g_barCnt, __ATOMIC_RELAXED, __HIP_MEMORY_SCOPE_AGENT) < target)
        __builtin_amdgcn_s_sleep(64);
      (void)__hip_atomic_load(&g_barCnt, __ATOMIC_ACQUIRE, __HIP_MEMORY_SCOPE_AGENT);  // inv L1/L2 once
    }
  }
  __syncthreads();
}

struct KP {
  const float* attn; const float* w_agg; const float* b_agg; const float* x;
  const float* W1; const float* att_src1; const float* att_dst1;
  const float* We1; const float* att_e1; const float* bias1;
  const float* W2; const float* att_src2; const float* att_dst2;
  const float* We2; const float* att_e2; const float* bias2;
  const float* W_lin; const float* b_lin; const int* bidx;
  float* edge_out; float* colSum; float* colCnt; float* z1; float* z2;
  float* gsum; float* gcnt; float* wev;
  float* h1; float* a_s1; float* a_d1; float* hh2; float* a_s2; float* a_d2;
  float* partials; float* out;
};

__global__ __launch_bounds__(256, 2) void megaK(KP p) {
  __shared__ float smem[6240];   // max user: phase B  pL[16][260] + hT[8][260]
  const int tid = threadIdx.x;
  const int b = blockIdx.x;

  // ---------- phase Z: zero reduction buffers (colSum|colCnt|z1|z2|gsum|gcnt) ----------
  {
    const int total = 7 * N + 520;
    int i = b * 256 + tid;
    if (i < total) p.colSum[i] = 0.f;
  }
  gridBarrier();

  // ---------- phase A: agg stripe (32 rows x 256 cols) + h1 chunk (4 nodes) ----------
  {
    float wreg[12];
#pragma unroll
    for (int k = 0; k < 12; ++k) wreg[k] = p.w_agg[k];
    const float bb = p.b_agg[0];
    const int i0 = (b >> 3) * 32, j0 = (b & 7) * 256;
    const int j = j0 + tid;
    float csA = 0.f, ccA = 0.f;
#pragma unroll 2
    for (int r = 0; r < 32; ++r) {
      int i = i0 + r;
      const float* pp = p.attn + (size_t)i * N + j;
      float v = bb;
#pragma unroll
      for (int k = 0; k < 12; ++k) v += wreg[k] * pp[(size_t)k * N * N];
      float e = v > 0.f ? v : 0.f;
      p.edge_out[(size_t)i * N + j] = e;
      if (e > 0.f && i != j) { csA += e; ccA += 1.f; }
    }
    atomicAdd(&p.colSum[j], csA);
    atomicAdd(&p.colCnt[j], ccA);

    // h1 = x @ W1, a_s1, a_d1; block 0 also computes we[]
    float* xr = smem;
    const int n0 = b * 4;
    if (b == 0) {
      float v1 = p.We1[tid] * p.att_e1[tid];
#pragma unroll
      for (int off = 32; off > 0; off >>= 1) v1 += __shfl_down(v1, off);
      int lane = tid & 63, wid = tid >> 6;
      if (lane == 0) p.wev[wid] = v1;
      float v2 = (tid < 64) ? p.We2[tid] * p.att_e2[tid] : 0.f;
#pragma unroll
      for (int off = 32; off > 0; off >>= 1) v2 += __shfl_down(v2, off);
      if (tid == 0) p.wev[4] = v2;
    }
    for (int t = tid; t < 512; t += 256) xr[t] = p.x[n0 * 128 + t];
    __syncthreads();
    float acc[4] = {0.f, 0.f, 0.f, 0.f};
    for (int k = 0; k < 128; ++k) {
      float wv = p.W1[k * 256 + tid];
#pragma unroll
      for (int r = 0; r < 4; ++r) acc[r] += xr[r * 128 + k] * wv;
    }
    float asw = p.att_src1[tid], adw = p.att_dst1[tid];
    int lane = tid & 63, head = tid >> 6;
#pragma unroll
    for (int r = 0; r < 4; ++r) {
      p.h1[(size_t)(n0 + r) * 256 + tid] = acc[r];
      float ps = acc[r] * asw, pd = acc[r] * adw;
#pragma unroll
      for (int off = 32; off > 0; off >>= 1) { ps += __shfl_down(ps, off); pd += __shfl_down(pd, off); }
      if (lane == 0) { p.a_s1[(n0 + r) * 4 + head] = ps; p.a_d1[(n0 + r) * 4 + head] = pd; }
    }
  }
  gridBarrier();

  // ---------- phase B: layer1 PV (unnormalized softmax, z1 via atomics) ----------
  {
    const int bx = b & 31, by = b >> 5;
    const int d0 = bx * 64;
    const int sBeg = by * 128;
    float (*hT)[260] = (float (*)[260])smem;            // [8][260]  (two halves)
    float (*pL)[260] = (float (*)[260])(smem + 2080);   // [16][260]
    float w0 = p.wev[0], w1 = p.wev[1], w2 = p.wev[2], w3 = p.wev[3];
    int ssp = tid & 15, dq = tid >> 4;
    float4 ad4[4];
    float me_[4];
#pragma unroll
    for (int q = 0; q < 4; ++q) {
      int d = d0 + dq * 4 + q;
      ad4[q] = *(const float4*)(p.a_d1 + d * 4);
      float c = p.colCnt[d];
      me_[q] = c > 0.f ? p.colSum[d] / c : 0.f;
    }
    float zac[4][4];
#pragma unroll
    for (int q = 0; q < 4; ++q)
#pragma unroll
      for (int h = 0; h < 4; ++h) zac[q][h] = 0.f;
    int dg = tid & 7;
    int cb = (tid >> 3) * 8;
    int hh = tid >> 6;
    float acc[8][8];
#pragma unroll
    for (int i = 0; i < 8; ++i)
#pragma unroll
      for (int jj = 0; jj < 8; ++jj) acc[i][jj] = 0.f;

    int c4 = (tid & 63) * 4;
    int rb2 = (tid >> 6) * 2;

#pragma unroll 1
    for (int s0 = sBeg; s0 < sBeg + 128; s0 += 16) {
      // p-compute: pL[ssp][h*64+dd] for all 16 ssp rows
      {
        int s = s0 + ssp;
        float4 as4 = *(const float4*)(p.a_s1 + s * 4);
        float4 av4 = *(const float4*)(p.edge_out + (size_t)s * N + d0 + dq * 4);
        float ev_[4] = {av4.x, av4.y, av4.z, av4.w};
        float pq[4][4];
#pragma unroll
        for (int q = 0; q < 4; ++q) {
          int d = d0 + dq * 4 + q;
          float av = ev_[q];
          float ev; bool inc;
          if (s == d) { ev = me_[q]; inc = true; } else { ev = av; inc = av > 0.f; }
          float p0 = inc ? __expf(lrelu(as4.x + ad4[q].x + ev * w0)) : 0.f;
          float p1 = inc ? __expf(lrelu(as4.y + ad4[q].y + ev * w1)) : 0.f;
          float p2 = inc ? __expf(lrelu(as4.z + ad4[q].z + ev * w2)) : 0.f;
          float p3 = inc ? __expf(lrelu(as4.w + ad4[q].w + ev * w3)) : 0.f;
          pq[0][q] = p0; pq[1][q] = p1; pq[2][q] = p2; pq[3][q] = p3;
          zac[q][0] += p0; zac[q][1] += p1; zac[q][2] += p2; zac[q][3] += p3;
        }
#pragma unroll
        for (int h = 0; h < 4; ++h)
          *(float4*)(&pL[ssp][h * 64 + dq * 4]) = make_float4(pq[h][0], pq[h][1], pq[h][2], pq[h][3]);
      }
      // half 0: stage hT rows 0..7 (= s0..s0+7)
#pragma unroll
      for (int p4 = 0; p4 < 2; ++p4) {
        int r = rb2 + p4;
        *(float4*)(&hT[r][c4]) = *(const float4*)(p.h1 + (size_t)(s0 + r) * 256 + c4);
      }
      __syncthreads();
#pragma unroll
      for (int ss = 0; ss < 8; ++ss) {
        float4 pA = *(const float4*)(&pL[ss][hh * 64 + dg * 8]);
        float4 pB = *(const float4*)(&pL[ss][hh * 64 + dg * 8 + 4]);
        float4 hA = *(const float4*)(&hT[ss][cb]);
        float4 hB = *(const float4*)(&hT[ss][cb + 4]);
        float pv[8] = {pA.x, pA.y, pA.z, pA.w, pB.x, pB.y, pB.z, pB.w};
        float hv[8] = {hA.x, hA.y, hA.z, hA.w, hB.x, hB.y, hB.z, hB.w};
#pragma unroll
        for (int di = 0; di < 8; ++di)
#pragma unroll
          for (int ci = 0; ci < 8; ++ci) acc[di][ci] += pv[di] * hv[ci];
      }
      __syncthreads();
      // half 1: stage hT rows 0..7 (= s0+8..s0+15)
#pragma unroll
      for (int p4 = 0; p4 < 2; ++p4) {
        int r = rb2 + p4;
        *(float4*)(&hT[r][c4]) = *(const float4*)(p.h1 + (size_t)(s0 + 8 + r) * 256 + c4);
      }
      __syncthreads();
#pragma unroll
      for (int ss = 8; ss < 16; ++ss) {
        float4 pA = *(const float4*)(&pL[ss][hh * 64 + dg * 8]);
        float4 pB = *(const float4*)(&pL[ss][hh * 64 + dg * 8 + 4]);
        float4 hA = *(const float4*)(&hT[ss - 8][cb]);
        float4 hB = *(const float4*)(&hT[ss - 8][cb + 4]);
        float pv[8] = {pA.x, pA.y, pA.z, pA.w, pB.x, pB.y, pB.z, pB.w};
        float hv[8] = {hA.x, hA.y, hA.z, hA.w, hB.x, hB.y, hB.z, hB.w};
#pragma unroll
        for (int di = 0; di < 8; ++di)
#pragma unroll
          for (int ci = 0; ci < 8; ++ci) acc[di][ci] += pv[di] * hv[ci];
      }
      __syncthreads();
    }
    float* outp = p.partials + (size_t)by * ((size_t)N * 256);
#pragma unroll
    for (int di = 0; di < 8; ++di) {
      size_t rowo = (size_t)(d0 + dg * 8 + di) * 256 + cb;
      *(float4*)(outp + rowo) = make_float4(acc[di][0], acc[di][1], acc[di][2], acc[di][3]);
      *(float4*)(outp + rowo + 4) = make_float4(acc[di][4], acc[di][5], acc[di][6], acc[di][7]);
    }
#pragma unroll
    for (int q = 0; q < 4; ++q)
#pragma unroll
      for (int h = 0; h < 4; ++h) {
        float v = zac[q][h];
        v += __shfl_down(v, 8); v += __shfl_down(v, 4);
        v += __shfl_down(v, 2); v += __shfl_down(v, 1);
        if (ssp == 0) atomicAdd(&p.z1[(d0 + dq * 4 + q) * 4 + h], v);
      }
  }
  gridBarrier();

  // ---------- phase C: layer1 finalize + h2 features ----------
  {
    float (*hr)[256] = (float (*)[256])smem;
    const int n0 = b * 4;
    for (int e = tid; e < 1024; e += 256) {
      int node = e >> 8, c = e & 255;
      size_t base = (size_t)(n0 + node) * 256 + c;
      float sAcc = 0.f;
#pragma unroll
      for (int q = 0; q < 16; ++q) sAcc += p.partials[(size_t)q * N * 256 + base];
      float a = sAcc / p.z1[(n0 + node) * 4 + (c >> 6)] + p.bias1[c];
      hr[node][c] = a > 0.f ? a : __expf(a) - 1.f;
    }
    __syncthreads();
    int c = tid & 63, nl = tid >> 6;
    float acc = 0.f;
    for (int k = 0; k < 256; ++k) acc += hr[nl][k] * p.W2[k * 64 + c];
    p.hh2[(size_t)(n0 + nl) * 64 + c] = acc;
    float ps = acc * p.att_src2[c], pd = acc * p.att_dst2[c];
#pragma unroll
    for (int off = 32; off > 0; off >>= 1) { ps += __shfl_down(ps, off); pd += __shfl_down(pd, off); }
    if (c == 0) { p.a_s2[n0 + nl] = ps; p.a_d2[n0 + nl] = pd; }
  }
  gridBarrier();

  // ---------- phase D: layer2 PV (unnormalized, z2 via atomics) ----------
  {
    const int bx = b & 15, by = b >> 4;
    const int d0 = bx * 128;
    const int sBeg = by * 64;
    float (*hT)[68]  = (float (*)[68])smem;             // [16][68]
    float (*pL)[132] = (float (*)[132])(smem + 1088);   // [16][132]
    float wE = p.wev[4];
    int ssp = tid & 15, dq = tid >> 4;
    float adv[8], me_[8];
#pragma unroll
    for (int q = 0; q < 8; ++q) {
      int d = d0 + dq * 8 + q;
      adv[q] = p.a_d2[d];
      float c = p.colCnt[d];
      me_[q] = c > 0.f ? p.colSum[d] / c : 0.f;
    }
    float zac[8];
#pragma unroll
    for (int q = 0; q < 8; ++q) zac[q] = 0.f;
    int dg = tid & 15;
    int cg2 = tid >> 4;
    float acc[8][4];
#pragma unroll
    for (int i = 0; i < 8; ++i)
#pragma unroll
      for (int jj = 0; jj < 4; ++jj) acc[i][jj] = 0.f;

    int stR = tid >> 4, stC = (tid & 15) * 4;

#pragma unroll 1
    for (int s0 = sBeg; s0 < sBeg + 64; s0 += 16) {
      *(float4*)(&hT[stR][stC]) = *(const float4*)(p.hh2 + (size_t)(s0 + stR) * 64 + stC);
      {
        int s = s0 + ssp;
        float asv = p.a_s2[s];
        float4 eA = *(const float4*)(p.edge_out + (size_t)s * N + d0 + dq * 8);
        float4 eB = *(const float4*)(p.edge_out + (size_t)s * N + d0 + dq * 8 + 4);
        float ev_[8] = {eA.x, eA.y, eA.z, eA.w, eB.x, eB.y, eB.z, eB.w};
        float pq[8];
#pragma unroll
        for (int q = 0; q < 8; ++q) {
          int d = d0 + dq * 8 + q;
          float av = ev_[q];
          float ev; bool inc;
          if (s == d) { ev = me_[q]; inc = true; } else { ev = av; inc = av > 0.f; }
          float pz = inc ? __expf(lrelu(asv + adv[q] + ev * wE)) : 0.f;
          pq[q] = pz;
          zac[q] += pz;
        }
        *(float4*)(&pL[ssp][dq * 8])     = make_float4(pq[0], pq[1], pq[2], pq[3]);
        *(float4*)(&pL[ssp][dq * 8 + 4]) = make_float4(pq[4], pq[5], pq[6], pq[7]);
      }
      __syncthreads();
#pragma unroll
      for (int ss = 0; ss < 16; ++ss) {
        float4 pA = *(const float4*)(&pL[ss][dg * 8]);
        float4 pB = *(const float4*)(&pL[ss][dg * 8 + 4]);
        float4 hA = *(const float4*)(&hT[ss][cg2 * 4]);
        float pv[8] = {pA.x, pA.y, pA.z, pA.w, pB.x, pB.y, pB.z, pB.w};
        float hv[4] = {hA.x, hA.y, hA.z, hA.w};
#pragma unroll
        for (int di = 0; di < 8; ++di)
#pragma unroll
          for (int ci = 0; ci < 4; ++ci) acc[di][ci] += pv[di] * hv[ci];
      }
      __syncthreads();
    }
    float* outp = p.partials + (size_t)by * ((size_t)N * 64);
#pragma unroll
    for (int di = 0; di < 8; ++di) {
      size_t rowo = (size_t)(d0 + dg * 8 + di) * 64 + cg2 * 4;
      *(float4*)(outp + rowo) = make_float4(acc[di][0], acc[di][1], acc[di][2], acc[di][3]);
    }
#pragma unroll
    for (int q = 0; q < 8; ++q) {
      float v = zac[q];
      v += __shfl_down(v, 8); v += __shfl_down(v, 4);
      v += __shfl_down(v, 2); v += __shfl_down(v, 1);
      if (ssp == 0) atomicAdd(&p.z2[d0 + dq * 8 + q], v);
    }
  }
  gridBarrier();

  // ---------- phase E: layer2 finalize + pooled sums ----------
  {
    int i = b * 256 + tid;
    int d = i >> 6, c = i & 63;
    float s = 0.f;
#pragma unroll
    for (int q = 0; q < 32; ++q) s += p.partials[(size_t)q * N * 64 + i];
    float a = s / p.z2[d] + p.bias2[c];
    float v = a > 0.f ? a : __expf(a) - 1.f;
    int g = p.bidx[d];
    atomicAdd(&p.gsum[g * 64 + c], v);
    if (c == 0) atomicAdd(&p.gcnt[g], 1.f);
  }
  gridBarrier();

  // ---------- final: global mean pool + linear (block 0 only) ----------
  if (b == 0) {
    float* gm   = smem;        // 512
    float* cnt_ = smem + 512;  // 8
    if (tid < NG) cnt_[tid] = p.gcnt[tid];
    __syncthreads();
    for (int e = tid; e < NG * 64; e += 256) {
      gm[e] = p.gsum[e] / fmaxf(cnt_[e >> 6], 1.f);
    }
    __syncthreads();
    if (tid < NG * 10) {
      int bb2 = tid / 10, oo = tid % 10;
      float accv = p.b_lin[oo];
      for (int k = 0; k < 64; ++k) accv += gm[bb2 * 64 + k] * p.W_lin[k * 10 + oo];
      p.out[bb2 * 10 + oo] = accv;
    }
  }
}

extern "C" void kernel_launch(void* const* d_in, const int* in_sizes, int n_in,
                              void* d_out, int out_size, void* d_ws, size_t ws_size,
                              hipStream_t stream) {
  KP hp;
  hp.x        = (const float*)d_in[0];
  hp.attn     = (const float*)d_in[1];
  hp.bidx     = (const int*)d_in[2];
  hp.w_agg    = (const float*)d_in[3];
  hp.b_agg    = (const float*)d_in[4];
  hp.W1       = (const float*)d_in[5];
  hp.att_src1 = (const float*)d_in[6];
  hp.att_dst1 = (const float*)d_in[7];
  hp.We1      = (const float*)d_in[8];
  hp.att_e1   = (const float*)d_in[9];
  hp.bias1    = (const float*)d_in[10];
  hp.W2       = (const float*)d_in[11];
  hp.att_src2 = (const float*)d_in[12];
  hp.att_dst2 = (const float*)d_in[13];
  hp.We2      = (const float*)d_in[14];
  hp.att_e2   = (const float*)d_in[15];
  hp.bias2    = (const float*)d_in[16];
  hp.W_lin    = (const float*)d_in[17];
  hp.b_lin    = (const float*)d_in[18];

  float* out = (float*)d_out;
  hp.out = out;
  hp.edge_out = out + 80;

  float* w = (float*)d_ws;
  size_t o = 0;
  float* zb = w + o; o += 7 * N + 1024;   // colSum|colCnt|z1(4N)|z2(N)|gsum(512)|gcnt(8)
  hp.wev  = w + o; o += 8;
  hp.h1   = w + o; o += (size_t)N * 256;
  hp.a_s1 = w + o; o += (size_t)N * 4;
  hp.a_d1 = w + o; o += (size_t)N * 4;
  hp.hh2  = w + o; o += (size_t)N * 64;
  hp.a_s2 = w + o; o += N;
  hp.a_d2 = w + o; o += N;
  hp.partials = w + o; o += (size_t)16 * N * 256;  // phase D reuses (needs 32*N*64 = half)

  hp.colSum = zb;
  hp.colCnt = zb + N;
  hp.z1     = zb + 2 * N;
  hp.z2     = zb + 6 * N;
  hp.gsum   = zb + 7 * N;
  hp.gcnt   = zb + 7 * N + 512;

  megaK<<<dim3(NBLK), dim3(256), 0, stream>>>(hp);
}

// Round 7
// 455.480 us; speedup vs baseline: 2.2289x; 1.4809x over previous
//
#include <hip/hip_runtime.h>

#define N 2048
#define NG 8

__device__ __forceinline__ float lrelu(float x) { return x > 0.f ? x : 0.2f * x; }

// NOTE: element type must be __fp16 (not _Float16) to match the return type of
// __builtin_amdgcn_cvt_pkrtz and the operand type of __builtin_amdgcn_fdot2 on
// this clang (round-6 compile failure: no implicit conversion between the two).
typedef __fp16 f16x2 __attribute__((ext_vector_type(2)));
__device__ __forceinline__ unsigned pkf16(float a, float b) {
  f16x2 h = __builtin_amdgcn_cvt_pkrtz(a, b);   // (a->lo, b->hi)
  union { f16x2 h; unsigned u; } cv; cv.h = h; return cv.u;
}
__device__ __forceinline__ f16x2 asf16x2(unsigned u) {
  union { unsigned u; f16x2 h; } cv; cv.u = u; return cv.h;
}

// ---------- fused: h1 (blocks 0..511) + agg/edge/colstats (blocks 512..4607) ----------
__global__ __launch_bounds__(256) void aggh1K(const float* __restrict__ attn,
                                              const float* __restrict__ w_agg,
                                              const float* __restrict__ b_agg,
                                              const float* __restrict__ x,
                                              const float* __restrict__ W1,
                                              const float* __restrict__ att_src1,
                                              const float* __restrict__ att_dst1,
                                              const float* __restrict__ We1, const float* __restrict__ att_e1,
                                              const float* __restrict__ We2, const float* __restrict__ att_e2,
                                              float* __restrict__ edge_out,
                                              float* __restrict__ colSum, float* __restrict__ colCnt,
                                              float* __restrict__ h1, float* __restrict__ a_s1, float* __restrict__ a_d1,
                                              float* __restrict__ we) {
  __shared__ float smem[512];  // h1: xr[4][128]; agg: [0..11]=wsh, [32..63]=cs, [64..95]=cc
  int tid = threadIdx.x;
  if (blockIdx.x < 512) {
    // ---- h1 = x @ W1, a_s1, a_d1; block 0 also computes we[] ----
    float* xr = smem;
    int n0 = blockIdx.x * 4;
    if (blockIdx.x == 0) {
      float v1 = We1[tid] * att_e1[tid];
#pragma unroll
      for (int off = 32; off > 0; off >>= 1) v1 += __shfl_down(v1, off);
      int lane = tid & 63, wid = tid >> 6;
      if (lane == 0) we[wid] = v1;
      float v2 = (tid < 64) ? We2[tid] * att_e2[tid] : 0.f;
#pragma unroll
      for (int off = 32; off > 0; off >>= 1) v2 += __shfl_down(v2, off);
      if (tid == 0) we[4] = v2;
    }
    for (int t = tid; t < 512; t += 256) xr[t] = x[n0 * 128 + t];
    __syncthreads();
    float acc[4] = {0.f, 0.f, 0.f, 0.f};
    for (int k = 0; k < 128; ++k) {
      float wv = W1[k * 256 + tid];
#pragma unroll
      for (int r = 0; r < 4; ++r) acc[r] += xr[r * 128 + k] * wv;
    }
    float asw = att_src1[tid], adw = att_dst1[tid];
    int lane = tid & 63, head = tid >> 6;
#pragma unroll
    for (int r = 0; r < 4; ++r) {
      h1[(size_t)(n0 + r) * 256 + tid] = acc[r];
      float ps = acc[r] * asw, pd = acc[r] * adw;
#pragma unroll
      for (int off = 32; off > 0; off >>= 1) { ps += __shfl_down(ps, off); pd += __shfl_down(pd, off); }
      if (lane == 0) { a_s1[(n0 + r) * 4 + head] = ps; a_d1[(n0 + r) * 4 + head] = pd; }
    }
  } else {
    // ---- agg: 1x1 conv over 12 maps, relu -> edge_out, column stats ----
    float* wsh = smem;
    float* cs = smem + 32;
    float* cc = smem + 64;
    int bidA = blockIdx.x - 512;
    int tx = tid & 31, ty = tid >> 5;
    if (tid < 12) wsh[tid] = w_agg[tid];
    if (tid < 32) { cs[tid] = 0.f; cc[tid] = 0.f; }
    __syncthreads();
    int i0 = (bidA >> 6) * 32, j0 = (bidA & 63) * 32;
    int j = j0 + tx;
    float bb = b_agg[0];
#pragma unroll
    for (int r = 0; r < 4; ++r) {
      int i = i0 + ty + 8 * r;
      const float* p = attn + (size_t)i * N + j;
      float v = bb;
#pragma unroll
      for (int k = 0; k < 12; ++k) v += wsh[k] * p[(size_t)k * N * N];
      float e = v > 0.f ? v : 0.f;
      edge_out[(size_t)i * N + j] = e;
      if (e > 0.f && i != j) { atomicAdd(&cs[tx], e); atomicAdd(&cc[tx], 1.f); }
    }
    __syncthreads();
    if (tid < 32) {
      atomicAdd(&colSum[j0 + tid], cs[tid]);
      atomicAdd(&colCnt[j0 + tid], cc[tid]);
    }
  }
}

// ---------- layer1 PV via f16x2 dot2 over s-pairs (z in exact f32) ----------
// grid (32,16): 64-d tile x 128-s chunk.
__global__ __launch_bounds__(256) void pv1K(const float* __restrict__ edge, const float* __restrict__ h1,
                                            const float* __restrict__ a_s1, const float* __restrict__ a_d1,
                                            const float* __restrict__ colSum, const float* __restrict__ colCnt,
                                            const float* __restrict__ we,
                                            float* __restrict__ partials, float* __restrict__ z1) {
  __shared__ unsigned pH[8][264];   // [s-pair][head*64+dd]  f16x2 = (p[2sp], p[2sp+1])
  __shared__ unsigned hH[8][264];   // [s-pair][c]           f16x2 = (h[2sp][c], h[2sp+1][c])
  int tid = threadIdx.x;
  int d0 = blockIdx.x * 64;
  int sBeg = blockIdx.y * 128;
  float w0 = we[0], w1 = we[1], w2 = we[2], w3 = we[3];
  // p-compute indexing
  int ssp = tid & 15, dq = tid >> 4;   // dd = dq*4+q
  float4 ad4[4];
  float me_[4];
#pragma unroll
  for (int q = 0; q < 4; ++q) {
    int d = d0 + dq * 4 + q;
    ad4[q] = *(const float4*)(a_d1 + d * 4);
    float c = colCnt[d];
    me_[q] = c > 0.f ? colSum[d] / c : 0.f;
  }
  float zac[4][4];
#pragma unroll
  for (int q = 0; q < 4; ++q)
#pragma unroll
    for (int h = 0; h < 4; ++h) zac[q][h] = 0.f;
  // dot2 indexing
  int dg = tid & 7;            // d = d0 + dg*8 + di
  int cb = (tid >> 3) * 8;     // global channel base (includes head)
  int hh = tid >> 6;           // head (wave-uniform)
  float acc[8][8];
#pragma unroll
  for (int i = 0; i < 8; ++i)
#pragma unroll
    for (int j = 0; j < 8; ++j) acc[i][j] = 0.f;

  int c4 = (tid & 63) * 4;
  int sg2 = (tid >> 6) * 2;

#pragma unroll 1
  for (int s0 = sBeg; s0 < sBeg + 128; s0 += 16) {
    // stage hH: pack row pairs (2sp, 2sp+1) as f16x2 while staging (same global volume)
#pragma unroll
    for (int p4 = 0; p4 < 2; ++p4) {
      int sp = sg2 + p4;
      float4 r0 = *(const float4*)(h1 + (size_t)(s0 + 2 * sp) * 256 + c4);
      float4 r1 = *(const float4*)(h1 + (size_t)(s0 + 2 * sp + 1) * 256 + c4);
      uint4 wv;
      wv.x = pkf16(r0.x, r1.x); wv.y = pkf16(r0.y, r1.y);
      wv.z = pkf16(r0.z, r1.z); wv.w = pkf16(r0.w, r1.w);
      *(uint4*)&hH[sp][c4] = wv;
    }
    // p-compute (f32, exact z), then pack s-pairs via shfl_xor(lane bit0 == s parity)
    {
      int s = s0 + ssp;
      float4 as4 = *(const float4*)(a_s1 + s * 4);
      float4 av4 = *(const float4*)(edge + (size_t)s * N + d0 + dq * 4);
      float ev_[4] = {av4.x, av4.y, av4.z, av4.w};
      float pq[4][4];
#pragma unroll
      for (int q = 0; q < 4; ++q) {
        int d = d0 + dq * 4 + q;
        float av = ev_[q];
        float ev; bool inc;
        if (s == d) { ev = me_[q]; inc = true; } else { ev = av; inc = av > 0.f; }
        float p0 = inc ? __expf(lrelu(as4.x + ad4[q].x + ev * w0)) : 0.f;
        float p1 = inc ? __expf(lrelu(as4.y + ad4[q].y + ev * w1)) : 0.f;
        float p2 = inc ? __expf(lrelu(as4.z + ad4[q].z + ev * w2)) : 0.f;
        float p3 = inc ? __expf(lrelu(as4.w + ad4[q].w + ev * w3)) : 0.f;
        pq[0][q] = p0; pq[1][q] = p1; pq[2][q] = p2; pq[3][q] = p3;
        zac[q][0] += p0; zac[q][1] += p1; zac[q][2] += p2; zac[q][3] += p3;
      }
      bool evn = (ssp & 1) == 0;
#pragma unroll
      for (int h = 0; h < 4; ++h) {
        float o0 = __shfl_xor(pq[h][0], 1);
        float o1 = __shfl_xor(pq[h][1], 1);
        float o2 = __shfl_xor(pq[h][2], 1);
        float o3 = __shfl_xor(pq[h][3], 1);
        if (evn) {
          uint4 wv;
          wv.x = pkf16(pq[h][0], o0); wv.y = pkf16(pq[h][1], o1);
          wv.z = pkf16(pq[h][2], o2); wv.w = pkf16(pq[h][3], o3);
          *(uint4*)&pH[ssp >> 1][h * 64 + dq * 4] = wv;
        }
      }
    }
    __syncthreads();
#pragma unroll
    for (int sp = 0; sp < 8; ++sp) {
      uint4 pa0 = *(const uint4*)&pH[sp][hh * 64 + dg * 8];
      uint4 pa1 = *(const uint4*)&pH[sp][hh * 64 + dg * 8 + 4];
      uint4 ha0 = *(const uint4*)&hH[sp][cb];
      uint4 ha1 = *(const uint4*)&hH[sp][cb + 4];
      f16x2 pv[8] = {asf16x2(pa0.x), asf16x2(pa0.y), asf16x2(pa0.z), asf16x2(pa0.w),
                     asf16x2(pa1.x), asf16x2(pa1.y), asf16x2(pa1.z), asf16x2(pa1.w)};
      f16x2 hv[8] = {asf16x2(ha0.x), asf16x2(ha0.y), asf16x2(ha0.z), asf16x2(ha0.w),
                     asf16x2(ha1.x), asf16x2(ha1.y), asf16x2(ha1.z), asf16x2(ha1.w)};
#pragma unroll
      for (int di = 0; di < 8; ++di)
#pragma unroll
        for (int ci = 0; ci < 8; ++ci)
          acc[di][ci] = __builtin_amdgcn_fdot2(pv[di], hv[ci], acc[di][ci], false);
    }
    __syncthreads();
  }
  float* outp = partials + (size_t)blockIdx.y * ((size_t)N * 256);
#pragma unroll
  for (int di = 0; di < 8; ++di) {
    size_t rowo = (size_t)(d0 + dg * 8 + di) * 256 + cb;
    *(float4*)(outp + rowo) = make_float4(acc[di][0], acc[di][1], acc[di][2], acc[di][3]);
    *(float4*)(outp + rowo + 4) = make_float4(acc[di][4], acc[di][5], acc[di][6], acc[di][7]);
  }
  // z reduction over ssp (16-lane groups), then atomics
#pragma unroll
  for (int q = 0; q < 4; ++q)
#pragma unroll
    for (int h = 0; h < 4; ++h) {
      float v = zac[q][h];
      v += __shfl_down(v, 8); v += __shfl_down(v, 4);
      v += __shfl_down(v, 2); v += __shfl_down(v, 1);
      if (ssp == 0) atomicAdd(&z1[(d0 + dq * 4 + q) * 4 + h], v);
    }
}

// ---------- layer2 features fused with layer1 finalize ----------
__global__ __launch_bounds__(256) void h2K(const float* __restrict__ partials, const float* __restrict__ z1,
                                           const float* __restrict__ bias1,
                                           const float* __restrict__ W2,
                                           const float* __restrict__ att_src2, const float* __restrict__ att_dst2,
                                           float* __restrict__ hh2, float* __restrict__ a_s2, float* __restrict__ a_d2) {
  __shared__ float hr[4][256];
  int tid = threadIdx.x;
  int n0 = blockIdx.x * 4;
  for (int e = tid; e < 1024; e += 256) {
    int node = e >> 8, c = e & 255;
    size_t base = (size_t)(n0 + node) * 256 + c;
    float sAcc = 0.f;
#pragma unroll
    for (int q = 0; q < 16; ++q) sAcc += partials[(size_t)q * N * 256 + base];
    float a = sAcc / z1[(n0 + node) * 4 + (c >> 6)] + bias1[c];
    hr[node][c] = a > 0.f ? a : __expf(a) - 1.f;
  }
  __syncthreads();
  int c = tid & 63, nl = tid >> 6;
  float acc = 0.f;
  for (int k = 0; k < 256; ++k) acc += hr[nl][k] * W2[k * 64 + c];
  hh2[(size_t)(n0 + nl) * 64 + c] = acc;
  float ps = acc * att_src2[c], pd = acc * att_dst2[c];
#pragma unroll
  for (int off = 32; off > 0; off >>= 1) { ps += __shfl_down(ps, off); pd += __shfl_down(pd, off); }
  if (c == 0) { a_s2[n0 + nl] = ps; a_d2[n0 + nl] = pd; }
}

// ---------- layer2 PV (unnormalized, z via atomics), grid (16,32) ----------
__global__ __launch_bounds__(256) void pv2K(const float* __restrict__ edge, const float* __restrict__ hh2,
                                            const float* __restrict__ a_s2, const float* __restrict__ a_d2,
                                            const float* __restrict__ colSum, const float* __restrict__ colCnt,
                                            const float* __restrict__ we,
                                            float* __restrict__ partials, float* __restrict__ z2) {
  __shared__ float hT[16][68];    // [ss][c]  c = 0..63
  __shared__ float pL[16][132];   // [ss][dd] dd = 0..127
  int tid = threadIdx.x;
  int d0 = blockIdx.x * 128;
  int sBeg = blockIdx.y * 64;
  float wE = we[4];
  int ssp = tid & 15, dq = tid >> 4;   // dd = dq*8+q
  float adv[8], me_[8];
#pragma unroll
  for (int q = 0; q < 8; ++q) {
    int d = d0 + dq * 8 + q;
    adv[q] = a_d2[d];
    float c = colCnt[d];
    me_[q] = c > 0.f ? colSum[d] / c : 0.f;
  }
  float zac[8];
#pragma unroll
  for (int q = 0; q < 8; ++q) zac[q] = 0.f;
  int dg = tid & 15;   // d = d0 + dg*8 + di
  int cg = tid >> 4;   // c = cg*4 + ci
  float acc[8][4];
#pragma unroll
  for (int i = 0; i < 8; ++i)
#pragma unroll
    for (int j = 0; j < 4; ++j) acc[i][j] = 0.f;

  int stR = tid >> 4, stC = (tid & 15) * 4;

#pragma unroll 1
  for (int s0 = sBeg; s0 < sBeg + 64; s0 += 16) {
    *(float4*)(&hT[stR][stC]) = *(const float4*)(hh2 + (size_t)(s0 + stR) * 64 + stC);
    {
      int s = s0 + ssp;
      float asv = a_s2[s];
      float4 eA = *(const float4*)(edge + (size_t)s * N + d0 + dq * 8);
      float4 eB = *(const float4*)(edge + (size_t)s * N + d0 + dq * 8 + 4);
      float ev_[8] = {eA.x, eA.y, eA.z, eA.w, eB.x, eB.y, eB.z, eB.w};
      float pq[8];
#pragma unroll
      for (int q = 0; q < 8; ++q) {
        int d = d0 + dq * 8 + q;
        float av = ev_[q];
        float ev; bool inc;
        if (s == d) { ev = me_[q]; inc = true; } else { ev = av; inc = av > 0.f; }
        float p = inc ? __expf(lrelu(asv + adv[q] + ev * wE)) : 0.f;
        pq[q] = p;
        zac[q] += p;
      }
      *(float4*)(&pL[ssp][dq * 8])     = make_float4(pq[0], pq[1], pq[2], pq[3]);
      *(float4*)(&pL[ssp][dq * 8 + 4]) = make_float4(pq[4], pq[5], pq[6], pq[7]);
    }
    __syncthreads();
#pragma unroll
    for (int ss = 0; ss < 16; ++ss) {
      float4 pA = *(const float4*)(&pL[ss][dg * 8]);
      float4 pB = *(const float4*)(&pL[ss][dg * 8 + 4]);
      float4 hA = *(const float4*)(&hT[ss][cg * 4]);
      float pv[8] = {pA.x, pA.y, pA.z, pA.w, pB.x, pB.y, pB.z, pB.w};
      float hv[4] = {hA.x, hA.y, hA.z, hA.w};
#pragma unroll
      for (int di = 0; di < 8; ++di)
#pragma unroll
        for (int ci = 0; ci < 4; ++ci) acc[di][ci] += pv[di] * hv[ci];
    }
    __syncthreads();
  }
  float* outp = partials + (size_t)blockIdx.y * ((size_t)N * 64);
#pragma unroll
  for (int di = 0; di < 8; ++di) {
    size_t rowo = (size_t)(d0 + dg * 8 + di) * 64 + cg * 4;
    *(float4*)(outp + rowo) = make_float4(acc[di][0], acc[di][1], acc[di][2], acc[di][3]);
  }
#pragma unroll
  for (int q = 0; q < 8; ++q) {
    float v = zac[q];
    v += __shfl_down(v, 8); v += __shfl_down(v, 4);
    v += __shfl_down(v, 2); v += __shfl_down(v, 1);
    if (ssp == 0) atomicAdd(&z2[d0 + dq * 8 + q], v);
  }
}

// ---------- layer2 finalize + pooled sums (atomics) + last-block final linear ----------
__global__ __launch_bounds__(256) void fin2poolK(const float* __restrict__ partials, const float* __restrict__ z2,
                                                 const float* __restrict__ bias2, const int* __restrict__ bidx,
                                                 const float* __restrict__ W_lin, const float* __restrict__ b_lin,
                                                 float* __restrict__ gsum, float* __restrict__ gcnt,
                                                 int* __restrict__ ticket, float* __restrict__ out) {
  int tid = threadIdx.x;
  int i = blockIdx.x * 256 + tid;
  int d = i >> 6, c = i & 63;
  float s = 0.f;
#pragma unroll
  for (int q = 0; q < 32; ++q) s += partials[(size_t)q * N * 64 + i];
  float a = s / z2[d] + bias2[c];
  float v = a > 0.f ? a : __expf(a) - 1.f;
  int g = bidx[d];
  atomicAdd(&gsum[g * 64 + c], v);
  if (c == 0) atomicAdd(&gcnt[g], 1.f);
  // release: every thread's gsum atomic device-visible BEFORE the ticket.
  __threadfence();
  __syncthreads();
  __shared__ int lastSh;
  if (tid == 0) {
    int t = atomicAdd(ticket, 1);
    lastSh = (t == (int)gridDim.x - 1) ? 1 : 0;
  }
  __syncthreads();
  if (lastSh) {
    __shared__ float gm[NG][64];
    __shared__ float cnt_[NG];
    if (tid < NG) cnt_[tid] = atomicAdd(&gcnt[tid], 0.f);
    __syncthreads();
    for (int e = tid; e < NG * 64; e += 256) {
      float sv = atomicAdd(&gsum[e], 0.f);
      gm[e >> 6][e & 63] = sv / fmaxf(cnt_[e >> 6], 1.f);
    }
    __syncthreads();
    if (tid < NG * 10) {
      int b = tid / 10, o = tid % 10;
      float accv = b_lin[o];
      for (int k = 0; k < 64; ++k) accv += gm[b][k] * W_lin[k * 10 + o];
      out[b * 10 + o] = accv;
    }
  }
}

extern "C" void kernel_launch(void* const* d_in, const int* in_sizes, int n_in,
                              void* d_out, int out_size, void* d_ws, size_t ws_size,
                              hipStream_t stream) {
  const float* x        = (const float*)d_in[0];
  const float* attn     = (const float*)d_in[1];
  const int*   bidx     = (const int*)d_in[2];
  const float* w_agg    = (const float*)d_in[3];
  const float* b_agg    = (const float*)d_in[4];
  const float* W1       = (const float*)d_in[5];
  const float* att_src1 = (const float*)d_in[6];
  const float* att_dst1 = (const float*)d_in[7];
  const float* We1      = (const float*)d_in[8];
  const float* att_e1   = (const float*)d_in[9];
  const float* bias1    = (const float*)d_in[10];
  const float* W2       = (const float*)d_in[11];
  const float* att_src2 = (const float*)d_in[12];
  const float* att_dst2 = (const float*)d_in[13];
  const float* We2      = (const float*)d_in[14];
  const float* att_e2   = (const float*)d_in[15];
  const float* bias2    = (const float*)d_in[16];
  const float* W_lin    = (const float*)d_in[17];
  const float* b_lin    = (const float*)d_in[18];

  float* out = (float*)d_out;
  float* edge_out = out + 80;

  float* w = (float*)d_ws;
  size_t o = 0;
  float* zb   = w + o; o += 7 * N + 1024;   // colSum|colCnt|z1(4N)|z2(N)|gsum(512)|gcnt(8)|ticket
  float* wev  = w + o; o += 8;
  float* h1   = w + o; o += (size_t)N * 256;
  float* a_s1 = w + o; o += (size_t)N * 4;
  float* a_d1 = w + o; o += (size_t)N * 4;
  float* hh2  = w + o; o += (size_t)N * 64;
  float* a_s2 = w + o; o += N;
  float* a_d2 = w + o; o += N;
  float* partials = w + o; o += (size_t)16 * N * 256;  // pv2 reuses (needs 32*N*64 = half)

  float* colSum = zb;
  float* colCnt = zb + N;
  float* z1     = zb + 2 * N;
  float* z2     = zb + 6 * N;
  float* gsum   = zb + 7 * N;
  float* gcnt   = zb + 7 * N + 512;
  int*   ticket = (int*)(zb + 7 * N + 520);

  (void)hipMemsetAsync(zb, 0, (7 * N + 1024) * sizeof(float), stream);
  aggh1K<<<4608, 256, 0, stream>>>(attn, w_agg, b_agg, x, W1, att_src1, att_dst1,
                                   We1, att_e1, We2, att_e2,
                                   edge_out, colSum, colCnt, h1, a_s1, a_d1, wev);
  pv1K<<<dim3(32, 16), 256, 0, stream>>>(edge_out, h1, a_s1, a_d1, colSum, colCnt, wev, partials, z1);
  h2K<<<512, 256, 0, stream>>>(partials, z1, bias1, W2, att_src2, att_dst2, hh2, a_s2, a_d2);
  pv2K<<<dim3(16, 32), 256, 0, stream>>>(edge_out, hh2, a_s2, a_d2, colSum, colCnt, wev, partials, z2);
  fin2poolK<<<512, 256, 0, stream>>>(partials, z2, bias2, bidx, W_lin, b_lin, gsum, gcnt, ticket, out);
}